// Round 1
// baseline (104.199 us; speedup 1.0000x reference)
//
#include <hip/hip_runtime.h>
#include <hip/hip_cooperative_groups.h>

namespace cg = cooperative_groups;

// Problem constants (from reference): N=128 nodes, H=2 heads, L=1024.
#define NN 128
#define HH 2
#define LL 1024
#define NH (NN * HH)          // 256 rows
#define NHL (NN * HH * LL)    // 262144 elements per (n,h,l) tensor
#define COLS (HH * LL)        // 2048 columns of the alpha matrix

// Fused kernel: phase 1 = per-(n,h) row scan (relu, cumsum -> Ss, decay
// recurrence -> Is -> alpha), phase 2 = node-mix matvec + pred.
// Grid = 256 blocks x 256 threads, 1 block/CU -> trivially co-resident, so a
// cooperative grid sync replaces the second kernel launch (saves one launch
// overhead + the inter-kernel drain).
__global__ __launch_bounds__(256) void fused_kernel(
    const float* __restrict__ x, const float* __restrict__ Amat,
    const float* __restrict__ taus, const float* __restrict__ r0d,
    float* __restrict__ out_pred, float* __restrict__ out_signal,
    float* __restrict__ out_tmatT, float* __restrict__ ws_alpha,
    float* __restrict__ ws_ss) {
  const int bid = blockIdx.x;
  const int tid = threadIdx.x;

  // ---------------- Phase 1: row scan (row = bid) ----------------
  {
    const int row = bid;  // n*H + h
    const int lane = tid & 63;
    const int wave = tid >> 6;

    const float4* xr = (const float4*)(x + (size_t)row * LL);
    float4 v = xr[tid];
    float s0 = fmaxf(v.x, 0.f);
    float s1 = fmaxf(v.y, 0.f);
    float s2 = fmaxf(v.z, 0.f);
    float s3 = fmaxf(v.w, 0.f);

    const float tau = taus[row];
    const float d = 1.f - 1.f / tau;  // == exp(log(1 - 1/tau))
    const float R0 = r0d[row];

    // thread-local inclusive prefix sums (chunk of 4)
    float c0 = s0, c1 = c0 + s1, c2 = c1 + s2, c3 = c2 + s3;
    // thread-local decay recurrence (zero incoming state)
    float l0 = s0;
    float l1 = fmaf(d, l0, s1);
    float l2 = fmaf(d, l1, s2);
    float l3 = fmaf(d, l2, s3);

    // in-wave weighted inclusive scan over (chunk sum, chunk-end state)
    float vs = c3;
    float vi = l3;
    float D = d * d;
    D = D * D;     // d^4
    float Dp = D;  // D^off
#pragma unroll
    for (int off = 1; off < 64; off <<= 1) {
      float ps = __shfl_up(vs, off);
      float pi = __shfl_up(vi, off);
      if (lane >= off) {
        vs += ps;
        vi = fmaf(Dp, pi, vi);
      }
      Dp *= Dp;
    }
    // Dp == D^64 == wave ratio W

    __shared__ float tw_s[4];
    __shared__ float tw_i[4];
    if (lane == 63) {
      tw_s[wave] = vs;
      tw_i[wave] = vi;
    }
    __syncthreads();

    // wave-incoming totals (sequential combine over earlier waves)
    float S_in = 0.f, I_in = 0.f;
    for (int u = 0; u < wave; ++u) {
      S_in += tw_s[u];
      I_in = fmaf(I_in, Dp, tw_i[u]);  // I = I*W + I_u
    }

    // per-lane exclusive (state at end of previous chunk, within wave)
    float es = __shfl_up(vs, 1);
    float ei = __shfl_up(vi, 1);
    if (lane == 0) {
      es = 0.f;
      ei = 0.f;
    }
    const float exs = S_in + es;
    // wave-incoming state decays D^lane before reaching this chunk
    const float state = fmaf(I_in, exp2f((float)lane * log2f(D)), ei);

    // finalize per element
    float cum0 = exs + c0, cum1 = exs + c1, cum2 = exs + c2, cum3 = exs + c3;
    float is0 = fmaf(d, state, s0);
    float is1 = fmaf(d, is0, s1);
    float is2 = fmaf(d, is1, s2);
    float is3 = fmaf(d, is2, s3);

    float4 sig = make_float4(s0, s1, s2, s3);
    float4 ss = make_float4(1.f - cum0, 1.f - cum1, 1.f - cum2, 1.f - cum3);
    float4 al = make_float4(1.f - __expf(-R0 * is0), 1.f - __expf(-R0 * is1),
                            1.f - __expf(-R0 * is2), 1.f - __expf(-R0 * is3));

    const size_t base = (size_t)row * LL / 4 + tid;
    ((float4*)(out_signal))[base] = sig;  // output 1: signal
    ((float4*)(ws_alpha))[base] = al;
    ((float4*)(ws_ss))[base] = ss;
  }

  // tmatT = Amat + I (16384 elements; first 4096 flat threads, float4 each).
  // Only reads Amat -> independent of phase 1/2, done before the grid sync.
  {
    const int fid = bid * 256 + tid;
    if (fid < NN * NN / 4) {
      float4 t = ((const float4*)Amat)[fid];
      const int e = fid << 2;
      if (((e + 0) % (NN + 1)) == 0) t.x += 1.f;
      if (((e + 1) % (NN + 1)) == 0) t.y += 1.f;
      if (((e + 2) % (NN + 1)) == 0) t.z += 1.f;
      if (((e + 3) % (NN + 1)) == 0) t.w += 1.f;
      ((float4*)out_tmatT)[fid] = t;
    }
  }

  // device-wide visibility of ws_alpha / ws_ss across XCDs
  cg::this_grid().sync();

  // ---------------- Phase 2: mix ----------------
  {
    const int rg = bid >> 3;                                 // 32 rowgroups
    const int cg_ = bid & 7;                                 // 8 colgroups
    const int col = (cg_ << 8) + tid;                        // 0..2047
    const int k0 = __builtin_amdgcn_readfirstlane(rg << 2);  // block-uniform

    const float* __restrict__ a0 = Amat + (k0 + 0) * NN;
    const float* __restrict__ a1 = Amat + (k0 + 1) * NN;
    const float* __restrict__ a2 = Amat + (k0 + 2) * NN;
    const float* __restrict__ a3 = Amat + (k0 + 3) * NN;

    // +I term
    float acc0 = ws_alpha[(size_t)(k0 + 0) * COLS + col];
    float acc1 = ws_alpha[(size_t)(k0 + 1) * COLS + col];
    float acc2 = ws_alpha[(size_t)(k0 + 2) * COLS + col];
    float acc3 = ws_alpha[(size_t)(k0 + 3) * COLS + col];

    const float* __restrict__ ac = ws_alpha + col;
#pragma unroll 8
    for (int m = 0; m < NN; ++m) {
      const float av = ac[(size_t)m * COLS];
      acc0 = fmaf(a0[m], av, acc0);
      acc1 = fmaf(a1[m], av, acc1);
      acc2 = fmaf(a2[m], av, acc2);
      acc3 = fmaf(a3[m], av, acc3);
    }

    out_pred[(size_t)(k0 + 0) * COLS + col] =
        acc0 * ws_ss[(size_t)(k0 + 0) * COLS + col];
    out_pred[(size_t)(k0 + 1) * COLS + col] =
        acc1 * ws_ss[(size_t)(k0 + 1) * COLS + col];
    out_pred[(size_t)(k0 + 2) * COLS + col] =
        acc2 * ws_ss[(size_t)(k0 + 2) * COLS + col];
    out_pred[(size_t)(k0 + 3) * COLS + col] =
        acc3 * ws_ss[(size_t)(k0 + 3) * COLS + col];
  }
}

extern "C" void kernel_launch(void* const* d_in, const int* in_sizes, int n_in,
                              void* d_out, int out_size, void* d_ws,
                              size_t ws_size, hipStream_t stream) {
  const float* x = (const float*)d_in[0];     // (128,2,1024)
  const float* Amat = (const float*)d_in[1];  // (128,128)
  const float* taus = (const float*)d_in[2];  // (128,2)
  const float* r0d = (const float*)d_in[3];   // (128,2)

  float* out = (float*)d_out;
  float* out_pred = out;             // (128,2,1024)
  float* out_signal = out + NHL;     // (128,2,1024)
  float* out_tmatT = out + 2 * NHL;  // (128,128) = Amat + I

  float* ws = (float*)d_ws;
  float* ws_alpha = ws;     // NHL floats
  float* ws_ss = ws + NHL;  // NHL floats

  void* args[] = {(void*)&x,        (void*)&Amat,       (void*)&taus,
                  (void*)&r0d,      (void*)&out_pred,   (void*)&out_signal,
                  (void*)&out_tmatT, (void*)&ws_alpha,  (void*)&ws_ss};
  hipLaunchCooperativeKernel((const void*)fused_kernel, dim3(NH), dim3(256),
                             args, 0, stream);
}